// Round 7
// baseline (148.290 us; speedup 1.0000x reference)
//
#include <hip/hip_runtime.h>

#define HH 512
#define WW 512
#define BB 64
#define HW (HH*WW)
#define CSTRIDE 40     // padded per-batch coeff stride (floats)
#define BGRP 16        // batches per block (4 y-groups)

typedef float v2f __attribute__((ext_vector_type(2)));
typedef float v4f __attribute__((ext_vector_type(4)));

// ---------------------------------------------------------------------------
// Compile-time construction + inversion of the 19x19 TPS system matrix.
// RBF rows pre-scaled by ln(2) so the kernel can use hw v_log_f32 (log2).
// ---------------------------------------------------------------------------
constexpr double cx_ln(double x) {
  int e = 0;
  while (x >= 2.0) { x *= 0.5; ++e; }
  while (x < 1.0)  { x *= 2.0; --e; }
  double z = (x - 1.0) / (x + 1.0);
  double z2 = z * z, term = z, sum = 0.0;
  for (int n = 1; n < 60; n += 2) { sum += term / n; term *= z2; }
  return 2.0 * sum + e * 0.69314718055994530942;
}

struct WMat { float w[19][16]; };

constexpr WMat build_wm() {
  const double Xc[4] = {-1.0, -1.0/3.0, 1.0/3.0, 1.0};
  double A[19][38] = {};
  for (int r = 0; r < 19; ++r) {
    for (int c = 0; c < 38; ++c) {
      double v = 0.0;
      if (c >= 19) {
        v = ((c - 19) == r) ? 1.0 : 0.0;
      } else if (r < 16 && c < 16) {
        double dx = Xc[r >> 2] - Xc[c >> 2];
        double dy = Xc[r & 3] - Xc[c & 3];
        double r2 = dx * dx + dy * dy;
        v = (r2 == 0.0) ? 0.0 : r2 * cx_ln(r2 + 1e-6);
      } else if (r < 16) {
        v = (c == 16) ? 1.0 : ((c == 17) ? Xc[r >> 2] : Xc[r & 3]);
      } else if (c < 16) {
        v = (r == 16) ? 1.0 : ((r == 17) ? Xc[c >> 2] : Xc[c & 3]);
      }
      A[r][c] = v;
    }
  }
  for (int k = 0; k < 19; ++k) {
    int best = k;
    double bv = A[k][k] < 0 ? -A[k][k] : A[k][k];
    for (int r = k + 1; r < 19; ++r) {
      double av = A[r][k] < 0 ? -A[r][k] : A[r][k];
      if (av > bv) { bv = av; best = r; }
    }
    if (best != k)
      for (int c = 0; c < 38; ++c) { double t = A[k][c]; A[k][c] = A[best][c]; A[best][c] = t; }
    double rp = 1.0 / A[k][k];
    for (int c = 0; c < 38; ++c) A[k][c] *= rp;
    for (int r = 0; r < 19; ++r) {
      if (r == k) continue;
      double f = A[r][k];
      for (int c = 0; c < 38; ++c) A[r][c] -= f * A[k][c];
    }
  }
  WMat wm = {};
  for (int i = 0; i < 19; ++i)
    for (int j = 0; j < 16; ++j)
      wm.w[i][j] = (float)(A[i][19 + j] * (i < 16 ? 0.69314718055994530942 : 1.0));
  return wm;
}

__device__ __constant__ WMat WM = build_wm();

__device__ __forceinline__ float fast_log2(float x) {
#if __has_builtin(__builtin_amdgcn_logf)
  return __builtin_amdgcn_logf(x);
#else
  return __log2f(x);
#endif
}

// ---------------------------------------------------------------------------
// Kernel 1: per-batch coefficients -> d_ws (tiny; lanes<38 each do a
// 16-length dot against the baked inverse).
// ---------------------------------------------------------------------------
__global__ __launch_bounds__(64) void tps_coeff_kernel(
    const float* __restrict__ sp, float* __restrict__ coeff) {
  const int b = blockIdx.x;
  const int tid = threadIdx.x;
  if (tid < 38) {
    const int i = tid >> 1, d = tid & 1;
    const float* s = sp + b * 32 + d;
    float acc = 0.0f;
#pragma unroll
    for (int j = 0; j < 16; ++j) acc = fmaf(WM.w[i][j], s[2 * j], acc);
    coeff[b * CSTRIDE + tid] = acc;
  }
}

// ---------------------------------------------------------------------------
// Kernel 2: compute-all-then-burst. Phase A: batch-independent RBF basis
// u2[16] (2 adjacent px per thread). Phase B: ALL 16 batch results computed
// into v4f res[16] (64 VGPR) with NO stores. Phase C: 16 back-to-back
// global_store_dwordx4 (16 KiB in flight per wave) to maximize store-issue
// duty cycle -- testing the theory that sparse store bursts (1-4 stores per
// ~600 cycles of compute) starve the write queue and cap effective write BW
// at ~2.7 TB/s vs the fill's 6.6 TB/s.
// ---------------------------------------------------------------------------
__global__ __launch_bounds__(256) void tps_grid_kernel(
    const float* __restrict__ coeff, float* __restrict__ out) {
  const int n0 = (blockIdx.x * 256 + threadIdx.x) * 2;  // 2 adjacent px, same row
  const int ix = n0 & (WW - 1);
  const int iy = n0 >> 9;
  const float step = 2.0f / 511.0f;
  const float gy = -1.0f + iy * step;
  const v2f gxv = {-1.0f + ix * step, -1.0f + (ix + 1) * step};
  const float Xc[4] = {-1.0f, -1.0f / 3.0f, 1.0f / 3.0f, 1.0f};

  float dy2[4];
#pragma unroll
  for (int j = 0; j < 4; ++j) { float t = gy - Xc[j]; dy2[j] = t * t; }

  v2f dxp[4];
#pragma unroll
  for (int i = 0; i < 4; ++i) {
    v2f t = gxv - Xc[i];
    dxp[i] = t * t + 1e-6f;   // eps folded here (dy2 has none)
  }

  // batch-independent RBF basis, pixel-pair packed: u2[k] = {u_k(px0), u_k(px1)}
  v2f u2[16];
#pragma unroll
  for (int k = 0; k < 16; ++k) {
    v2f t = dxp[k >> 2] + dy2[k & 3];                   // v_pk_add_f32
    u2[k] = t * (v2f){fast_log2(t.x), fast_log2(t.y)};  // 2 logs + pk_mul
  }

  const int b0 = blockIdx.y * BGRP;

  // ---- phase B: all batch results into registers, zero stores ----
  v4f res[BGRP];
#pragma unroll
  for (int bi = 0; bi < BGRP; ++bi) {
    const float* __restrict__ c = coeff + (b0 + bi) * CSTRIDE;  // wave-uniform
    float cc[38];
#pragma unroll
    for (int i = 0; i < 38; ++i) cc[i] = c[i];          // uniform -> s_load

    v2f accx = cc[32] + gxv * cc[34] + gy * cc[36];     // {x(px0), x(px1)}
    v2f accy = cc[33] + gxv * cc[35] + gy * cc[37];
#pragma unroll
    for (int k = 0; k < 16; ++k) {
      accx += u2[k] * cc[2 * k];                        // v_pk_fma, SGPR coeff
      accy += u2[k] * cc[2 * k + 1];
    }
    res[bi] = (v4f){accx.x, accy.x, accx.y, accy.y};
  }

  // ---- phase C: 16 stores back-to-back (max store-issue density) ----
  float* op = out + (size_t)((size_t)b0 * HW + n0) * 2;
#pragma unroll
  for (int bi = 0; bi < BGRP; ++bi) {
    *(v4f*)op = res[bi];
    op += (size_t)HW * 2;
  }
}

extern "C" void kernel_launch(void* const* d_in, const int* in_sizes, int n_in,
                              void* d_out, int out_size, void* d_ws, size_t ws_size,
                              hipStream_t stream) {
  const float* sp = (const float*)d_in[0];   // [B, K, 2] fp32
  float* out = (float*)d_out;                // [B, H, W, 2] fp32
  float* coeff = (float*)d_ws;               // BB * CSTRIDE floats

  tps_coeff_kernel<<<BB, 64, 0, stream>>>(sp, coeff);

  dim3 grid(HW / 512, BB / BGRP);            // 512 px per block x, 4 batch-groups y
  tps_grid_kernel<<<grid, 256, 0, stream>>>(coeff, out);
}